// Round 3
// baseline (164.394 us; speedup 1.0000x reference)
//
#include <hip/hip_runtime.h>

typedef unsigned short u16;
typedef unsigned int u32;
typedef __bf16 bf16x8 __attribute__((ext_vector_type(8)));
typedef float f32x4 __attribute__((ext_vector_type(4)));
typedef float f32x16 __attribute__((ext_vector_type(16)));
typedef u32 u32x2 __attribute__((ext_vector_type(2)));
typedef u32 u32x4 __attribute__((ext_vector_type(4)));

#define NB 4
#define NS 2048
#define ND 192
#define NH 8
#define HD 24
#define NM (NB*NS)          // 8192 rows
#define N3 (3*ND)           // 576
#define NBH (NB*NH)         // 32
#define NROWS (NBH*NS)      // 65536 partial rows per part

#define LOG2E 1.4426950408889634f
// 1/sqrt(24) * log2(e): fold softmax scale and exp->exp2 conversion into Q
#define QSCALE (0.20412414523193152f * 1.4426950408889634f)

__device__ __forceinline__ u16 f2bf(float f){
  union { float f; unsigned u; } a; a.f = f;
  unsigned r = a.u + 0x7fffu + ((a.u >> 16) & 1u);   // round-to-nearest-even
  return (u16)(r >> 16);
}
__device__ __forceinline__ float b2f(u16 h){
  union { u32 u; float f; } a; a.u = ((u32)h) << 16; return a.f;
}
__device__ __forceinline__ u32 cvtpk(float lo, float hi){
  u32 r; asm("v_cvt_pk_bf16_f32 %0, %1, %2" : "=v"(r) : "v"(lo), "v"(hi)); return r;
}
// swaps high 32 lanes of a with low 32 lanes of b
__device__ __forceinline__ void pswap(u32 &a, u32 &b){
  asm("v_permlane32_swap_b32 %0, %1" : "+v"(a), "+v"(b));
}

// ---------------------------------------------------------------- prep ----
// seg A: x fp32 -> xb bf16 (1536 blocks)
// seg B: w_attn [192][576] -> wta [576][192] bf16 (27 blocks, LDS transpose)
// seg C: w_proj [192][192] -> wtp [192][192] bf16 (9 blocks)
__device__ __forceinline__ void transpose64(
    const float* __restrict__ src, int srcN, u16* __restrict__ dst, int dstK,
    int k0, int n0, u16 (*sh)[68], int tid)
{
  int r = tid >> 2, cs = tid & 3;
  const float* sp = src + (size_t)(k0 + r)*srcN + n0 + cs*16;
  #pragma unroll
  for (int q = 0; q < 4; ++q) {
    float4 v = *(const float4*)(sp + q*4);
    u16 o[4] = { f2bf(v.x), f2bf(v.y), f2bf(v.z), f2bf(v.w) };
    *(u32x2*)&sh[r][cs*16 + q*4] = *(const u32x2*)o;
  }
  __syncthreads();
  int n = tid >> 2, ks = tid & 3;
  u16 tmp[16];
  #pragma unroll
  for (int j = 0; j < 16; ++j) tmp[j] = sh[ks*16 + j][n];
  u16* dp = dst + (size_t)(n0 + n)*dstK + k0 + ks*16;
  *(u32x4*)dp       = *(const u32x4*)tmp;
  *(u32x4*)(dp + 8) = *(const u32x4*)(tmp + 8);
}

__global__ __launch_bounds__(256) void prep_kernel(
    const float* __restrict__ x, const float* __restrict__ w_attn,
    const float* __restrict__ w_proj,
    u16* __restrict__ xb, u16* __restrict__ wta, u16* __restrict__ wtp)
{
  __shared__ u16 sh[64][68];
  const int bid = blockIdx.x, tid = threadIdx.x;
  if (bid < 1536) {                                  // x -> bf16
    int i = bid*256 + tid;
    float4 v = reinterpret_cast<const float4*>(x)[i];
    u16 o[4] = { f2bf(v.x), f2bf(v.y), f2bf(v.z), f2bf(v.w) };
    *reinterpret_cast<u32x2*>(xb + (size_t)i*4) = *(const u32x2*)o;
  } else if (bid < 1536 + 27) {                      // w_attn transpose
    int t = bid - 1536; int kt = t/9, nt = t%9;
    transpose64(w_attn, N3, wta, ND, kt*64, nt*64, sh, tid);
  } else {                                           // w_proj transpose
    int t = bid - 1563; int kt = t/3, nt = t%3;
    transpose64(w_proj, ND, wtp, ND, kt*64, nt*64, sh, tid);
  }
}

// ----------------------------------------------------------------- qkv ----
// [8192,192] @ [192,576] + b.  96-wide n-tiles (4 heads exactly).
// Q/K -> qp/kp [b][s][h][32] as FULL 64B rows (d24 = mask/1.0 fold, pad=0)
// V   -> vtp [b][h][32][s] via LDS re-tile, 64B-contiguous segments;
//        row d=24 = 1.0 (softmax-denominator ones-row trick)
__global__ __launch_bounds__(256) void qkv_kernel(
    const u16* __restrict__ xb, const u16* __restrict__ wta,
    const float* __restrict__ b_attn, const float* __restrict__ mask0,
    u16* __restrict__ qp, u16* __restrict__ kp, u16* __restrict__ vtp)
{
  __shared__ u16 tile[96*72];    // V path: [96][72]; Q/K path: [64][104]
  const int m0 = blockIdx.x*64, n0 = blockIdx.y*96;
  const int tid = threadIdx.x;
  const int w = tid >> 6, lane = tid & 63, c = lane & 15, g = lane >> 4;
  f32x4 acc[6] = {};
  const int ar = m0 + w*16 + c;
  #pragma unroll
  for (int ks = 0; ks < 6; ++ks) {
    bf16x8 af = *(const bf16x8*)(xb + (size_t)ar*ND + ks*32 + g*8);
    #pragma unroll
    for (int t = 0; t < 6; ++t) {
      bf16x8 bfr = *(const bf16x8*)(wta + (size_t)(n0 + t*16 + c)*ND + ks*32 + g*8);
      acc[t] = __builtin_amdgcn_mfma_f32_16x16x32_bf16(af, bfr, acc[t], 0, 0, 0);
    }
  }
  const int b = m0 >> 11, sb = m0 & (NS-1);
  if (n0 >= 384) {                                   // ---- V tiles ----
    const int h0 = (n0 - 384)/HD;                    // 0 or 4
    #pragma unroll
    for (int t = 0; t < 6; ++t) {
      float bias = b_attn[n0 + t*16 + c];
      #pragma unroll
      for (int r = 0; r < 4; ++r)
        tile[(t*16 + c)*72 + w*16 + g*4 + r] = f2bf(acc[t][r] + bias);
    }
    __syncthreads();
    if (tid < 200) {                                 // 96 data rows + 4 ones rows, 2 segs
      int row = tid >> 1, seg = tid & 1;
      if (row < 96) {
        int hl = row / HD, dv = row % HD;
        u16* dst = vtp + ((size_t)((b*NH + h0 + hl)*32 + dv))*NS + sb + seg*32;
        const u16* src = &tile[row*72 + seg*32];
        #pragma unroll
        for (int q = 0; q < 4; ++q)
          *(u32x4*)(dst + q*8) = *(const u32x4*)(src + q*8);
      } else {
        int hl = row - 96;
        u16* dst = vtp + ((size_t)((b*NH + h0 + hl)*32 + 24))*NS + sb + seg*32;
        u16 ones[8] = {0x3F80,0x3F80,0x3F80,0x3F80,0x3F80,0x3F80,0x3F80,0x3F80};
        #pragma unroll
        for (int q = 0; q < 4; ++q)
          *(u32x4*)(dst + q*8) = *(const u32x4*)ones;
      }
    }
  } else {                                           // ---- Q/K tiles ----
    const bool isQ = (n0 < 192);
    const float scl = isQ ? QSCALE : 1.0f;
    #pragma unroll
    for (int t = 0; t < 6; ++t) {
      float bias = b_attn[n0 + t*16 + c];
      #pragma unroll
      for (int r = 0; r < 4; ++r)
        tile[(w*16 + g*4 + r)*104 + t*16 + c] = f2bf((acc[t][r] + bias)*scl);
    }
    __syncthreads();
    int row = tid >> 2, run = tid & 3;
    int h0 = (n0 % 192)/HD;                          // 0 or 4
    u16 d24 = isQ ? (u16)0x3F80
                  : f2bf(mask0[b*NS + sb + row] * LOG2E);
    u16 buf[32];
    #pragma unroll
    for (int j = 0; j < 24; ++j) buf[j] = tile[row*104 + run*24 + j];
    buf[24] = d24;
    #pragma unroll
    for (int j = 25; j < 32; ++j) buf[j] = 0;
    u16* dst = (isQ ? qp : kp)
             + ((size_t)((b*NS + sb + row)*NH + h0 + run))*32;
    #pragma unroll
    for (int q = 0; q < 4; ++q)
      *(u32x4*)(dst + q*8) = *(const u32x4*)(buf + q*8);
  }
}

// ---------------------------------------------------------------- attn ----
// 1 wave per block, 32 q-rows, kv split in 2 parts (blockIdx.z).
// S^T = mfma(K,Q); softmax in-register; denominator via V ones-row;
// partial (unnormalized O + l, running max m) written to po/pmf.
__global__ __launch_bounds__(64) void attn_kernel(
    const u16* __restrict__ qp, const u16* __restrict__ kp,
    const u16* __restrict__ vtp, u16* __restrict__ po, float* __restrict__ pmf)
{
  const int qt = 63 - (int)blockIdx.x;               // heavy tiles first
  const int bh = blockIdx.y;
  const int part = blockIdx.z;
  const int b = bh >> 3, h = bh & 7;
  const int lane = threadIdx.x, c = lane & 31, hi = lane >> 5;
  const int q0 = qt*32;
  const int nt = qt + 1, halfn = (nt + 1) >> 1;
  const int t0 = part ? halfn : 0;
  const int t1 = part ? nt : halfn;

  const int pidx = part*NROWS + bh*NS + q0 + c;
  u16* porow = po + (size_t)pidx*32;

  if (t0 >= t1) {                                    // empty part (qt==0,p==1)
    u32x2 z = {0,0};
    #pragma unroll
    for (int rr = 0; rr < 4; ++rr) *(u32x2*)(porow + rr*8 + hi*4) = z;
    if (hi == 0) pmf[pidx] = -3.0e38f;
    return;
  }

  const size_t rowstride = NH*32;                    // 256 u16 per s-row
  const size_t qkbase = (size_t)b*NS*rowstride + h*32;
  const size_t vbase  = ((size_t)(bh*32 + c))*NS;

  const u16* qrow = qp + qkbase + (size_t)(q0 + c)*rowstride;
  bf16x8 qf0 = *(const bf16x8*)(qrow + hi*8);
  bf16x8 qf1 = *(const bf16x8*)(qrow + 16 + hi*8);

  f32x16 o = {0};
  const f32x16 z16 = {0};
  float m = 0.f;

  // prologue: tile t0 frags
  const u16* k0row = kp + qkbase + (size_t)(t0*32 + c)*rowstride;
  bf16x8 ka0 = *(const bf16x8*)(k0row + hi*8);
  bf16x8 ka1 = *(const bf16x8*)(k0row + 16 + hi*8);
  bf16x8 va0 = *(const bf16x8*)(vtp + vbase + t0*32 + hi*8);
  bf16x8 va1 = *(const bf16x8*)(vtp + vbase + t0*32 + 16 + hi*8);

  for (int jt = t0; jt < t1; ++jt) {
    const int k0 = jt*32;
    const int kn = ((jt + 1 < t1) ? jt + 1 : jt)*32; // prefetch next (clamped)
    const u16* knrow = kp + qkbase + (size_t)(kn + c)*rowstride;
    bf16x8 kb0 = *(const bf16x8*)(knrow + hi*8);
    bf16x8 kb1 = *(const bf16x8*)(knrow + 16 + hi*8);
    bf16x8 vb0 = *(const bf16x8*)(vtp + vbase + kn + hi*8);
    bf16x8 vb1 = *(const bf16x8*)(vtp + vbase + kn + 16 + hi*8);

    f32x16 st = __builtin_amdgcn_mfma_f32_32x32x16_bf16(ka0, qf0, z16, 0, 0, 0);
    st        = __builtin_amdgcn_mfma_f32_32x32x16_bf16(ka1, qf1, st,  0, 0, 0);

    // causal mask (diag tile only) + per-lane max
    float pm = -3.0e38f;
    if (jt == qt) {
      #pragma unroll
      for (int r = 0; r < 16; ++r) {
        int krel = (r & 3) + 8*(r >> 2) + 4*hi;
        float s = (k0 + krel > q0 + c) ? -3.0e38f : st[r];
        st[r] = s; pm = fmaxf(pm, s);
      }
    } else {
      #pragma unroll
      for (int r = 0; r < 16; ++r) pm = fmaxf(pm, st[r]);
    }

    if (!__all(pm - m <= 8.f)) {                     // rare rescale path
      float pm2 = fmaxf(pm, __shfl_xor(pm, 32));
      float mn = fmaxf(m, pm2);
      float al = __builtin_amdgcn_exp2f(m - mn);
      #pragma unroll
      for (int r = 0; r < 16; ++r) o[r] *= al;
      m = mn;
    }

    #pragma unroll
    for (int r = 0; r < 16; ++r)
      st[r] = __builtin_amdgcn_exp2f(st[r] - m);

    // P^T -> B-frags: cvt_pk pairs + permlane32_swap (fills 2 words each)
    u32 a0 = cvtpk(st[0], st[1]),  b0 = cvtpk(st[4], st[5]);
    u32 a1 = cvtpk(st[2], st[3]),  b1 = cvtpk(st[6], st[7]);
    pswap(a0, b0); pswap(a1, b1);
    u32 a2 = cvtpk(st[8], st[9]),  b2 = cvtpk(st[12], st[13]);
    u32 a3 = cvtpk(st[10], st[11]), b3 = cvtpk(st[14], st[15]);
    pswap(a2, b2); pswap(a3, b3);
    union { u32 w[4]; bf16x8 v; } pf0, pf1;
    pf0.w[0] = a0; pf0.w[1] = a1; pf0.w[2] = b0; pf0.w[3] = b1;
    pf1.w[0] = a2; pf1.w[1] = a3; pf1.w[2] = b2; pf1.w[3] = b3;

    o = __builtin_amdgcn_mfma_f32_32x32x16_bf16(va0, pf0.v, o, 0, 0, 0);
    o = __builtin_amdgcn_mfma_f32_32x32x16_bf16(va1, pf1.v, o, 0, 0, 0);

    ka0 = kb0; ka1 = kb1; va0 = vb0; va1 = vb1;
  }

  // epilogue: write unnormalized partial (l rides in channel d=24)
  #pragma unroll
  for (int rr = 0; rr < 4; ++rr) {
    u32 lo = cvtpk(o[rr*4 + 0], o[rr*4 + 1]);
    u32 hi2 = cvtpk(o[rr*4 + 2], o[rr*4 + 3]);
    u32x2 wv = {lo, hi2};
    *(u32x2*)(porow + rr*8 + hi*4) = wv;
  }
  if (hi == 0) pmf[pidx] = m;
}

// --------------------------------------------------------------- merge ----
// combine the two kv-partials, normalize, emit ao [B,S,D] bf16
__global__ __launch_bounds__(256) void merge_kernel(
    const u16* __restrict__ po, const float* __restrict__ pmf,
    u16* __restrict__ ao)
{
  int i = blockIdx.x*256 + threadIdx.x;              // 65536 = (bh, q)
  int bh = i >> 11, q = i & (NS-1);
  int b = bh >> 3, h = bh & 7;
  float m1 = pmf[i], m2 = pmf[NROWS + i];
  float M = fmaxf(m1, m2);
  float w1 = __builtin_amdgcn_exp2f(m1 - M);
  float w2 = __builtin_amdgcn_exp2f(m2 - M);
  const u16* r1 = po + (size_t)i*32;
  const u16* r2 = r1 + (size_t)NROWS*32;
  u16 a1[32], a2[32];
  #pragma unroll
  for (int q4 = 0; q4 < 4; ++q4) {
    *(u32x4*)(a1 + q4*8) = *(const u32x4*)(r1 + q4*8);
    *(u32x4*)(a2 + q4*8) = *(const u32x4*)(r2 + q4*8);
  }
  float l = b2f(a1[24])*w1 + b2f(a2[24])*w2;
  float inv = 1.0f / l;
  u16 ob[24];
  #pragma unroll
  for (int d = 0; d < 24; ++d)
    ob[d] = f2bf((b2f(a1[d])*w1 + b2f(a2[d])*w2)*inv);
  u16* dst = ao + ((size_t)(b*NS + q))*ND + h*HD;
  #pragma unroll
  for (int q4 = 0; q4 < 3; ++q4)
    *(u32x4*)(dst + q4*8) = *(const u32x4*)(ob + q4*8);
}

// ---------------------------------------------------------------- proj ----
__global__ __launch_bounds__(256) void proj_kernel(
    const u16* __restrict__ ao, const u16* __restrict__ wtp,
    const float* __restrict__ bp, float* __restrict__ out)
{
  const int m0 = blockIdx.x*64, n0 = blockIdx.y*64;
  const int tid = threadIdx.x;
  const int w = tid >> 6, lane = tid & 63, c = lane & 15, g = lane >> 4;
  f32x4 acc[4] = {};
  const int ar = m0 + w*16 + c;
  #pragma unroll
  for (int ks = 0; ks < 6; ++ks) {
    bf16x8 af = *(const bf16x8*)(ao + (size_t)ar*ND + ks*32 + g*8);
    #pragma unroll
    for (int t = 0; t < 4; ++t) {
      bf16x8 bfr = *(const bf16x8*)(wtp + (size_t)(n0 + t*16 + c)*ND + ks*32 + g*8);
      acc[t] = __builtin_amdgcn_mfma_f32_16x16x32_bf16(af, bfr, acc[t], 0, 0, 0);
    }
  }
  #pragma unroll
  for (int t = 0; t < 4; ++t) {
    int n = n0 + t*16 + c;
    float bias = bp[n];
    #pragma unroll
    for (int r = 0; r < 4; ++r) {
      int mm = m0 + w*16 + g*4 + r;
      out[(size_t)mm*ND + n] = acc[t][r] + bias;
    }
  }
}

// -------------------------------------------------------------- launch ----
extern "C" void kernel_launch(void* const* d_in, const int* in_sizes, int n_in,
                              void* d_out, int out_size, void* d_ws, size_t ws_size,
                              hipStream_t stream)
{
  const float* x      = (const float*)d_in[0];
  const float* mask0  = (const float*)d_in[1];
  const float* w_attn = (const float*)d_in[2];
  const float* b_attn = (const float*)d_in[3];
  const float* w_proj = (const float*)d_in[4];
  const float* b_proj = (const float*)d_in[5];
  float* out = (float*)d_out;

  char* ws = (char*)d_ws;
  u16*   qp  = (u16*)(ws);                                  // 4 MB [b][s][h][32]
  u16*   kp  = (u16*)(ws + ((size_t)4  << 20));             // 4 MB [b][s][h][32]
  u16*   vtp = (u16*)(ws + ((size_t)8  << 20));             // 4 MB [b][h][32][s]
  u16*   xb  = (u16*)(ws + ((size_t)12 << 20));             // 3 MB x bf16
  u16*   wta = (u16*)(ws + ((size_t)15 << 20));             // 216 KB
  u16*   wtp = (u16*)(ws + ((size_t)15 << 20) + 256*1024);  // 72 KB
  u16*   ao  = (u16*)(ws + ((size_t)15 << 20) + 512*1024);  // 3 MB attn out bf16
  u16*   po  = (u16*)(ws + ((size_t)18 << 20) + 512*1024);  // 8 MB partials
  float* pmf = (float*)(ws + ((size_t)26 << 20) + 512*1024);// 512 KB running max
  // total ws use: 27 MB. No memset needed: every read byte is written.

  prep_kernel<<<1572, 256, 0, stream>>>(x, w_attn, w_proj, xb, wta, wtp);
  qkv_kernel<<<dim3(NM/64, 6), 256, 0, stream>>>(xb, wta, b_attn, mask0,
                                                 qp, kp, vtp);
  attn_kernel<<<dim3(64, NBH, 2), 64, 0, stream>>>(qp, kp, vtp, po, pmf);
  merge_kernel<<<256, 256, 0, stream>>>(po, pmf, ao);
  proj_kernel<<<dim3(NM/64, ND/64), 256, 0, stream>>>(ao, wtp, b_proj, out);
}

// Round 4
// 139.318 us; speedup vs baseline: 1.1800x; 1.1800x over previous
//
#include <hip/hip_runtime.h>

typedef unsigned short u16;
typedef unsigned int u32;
typedef __bf16 bf16x8 __attribute__((ext_vector_type(8)));
typedef float f32x4 __attribute__((ext_vector_type(4)));
typedef float f32x16 __attribute__((ext_vector_type(16)));
typedef u32 u32x2 __attribute__((ext_vector_type(2)));
typedef u32 u32x4 __attribute__((ext_vector_type(4)));

#define NB 4
#define NS 2048
#define ND 192
#define NH 8
#define HD 24
#define NM (NB*NS)          // 8192 rows
#define N3 (3*ND)           // 576
#define NBH (NB*NH)         // 32

#define LOG2E 1.4426950408889634f
// 1/sqrt(24) * log2(e): fold softmax scale and exp->exp2 conversion into Q
#define QSCALE (0.20412414523193152f * 1.4426950408889634f)

__device__ __forceinline__ u16 f2bf(float f){
  union { float f; unsigned u; } a; a.f = f;
  unsigned r = a.u + 0x7fffu + ((a.u >> 16) & 1u);   // round-to-nearest-even
  return (u16)(r >> 16);
}
__device__ __forceinline__ u32 cvtpk(float lo, float hi){
  u32 r; asm("v_cvt_pk_bf16_f32 %0, %1, %2" : "=v"(r) : "v"(lo), "v"(hi)); return r;
}
// swaps high 32 lanes of a with low 32 lanes of b
__device__ __forceinline__ void pswap(u32 &a, u32 &b){
  asm("v_permlane32_swap_b32 %0, %1" : "+v"(a), "+v"(b));
}

// ---------------------------------------------------------------- prep ----
__device__ __forceinline__ void transpose64(
    const float* __restrict__ src, int srcN, u16* __restrict__ dst, int dstK,
    int k0, int n0, u16 (*sh)[68], int tid)
{
  int r = tid >> 2, cs = tid & 3;
  const float* sp = src + (size_t)(k0 + r)*srcN + n0 + cs*16;
  #pragma unroll
  for (int q = 0; q < 4; ++q) {
    float4 v = *(const float4*)(sp + q*4);
    u16 o[4] = { f2bf(v.x), f2bf(v.y), f2bf(v.z), f2bf(v.w) };
    *(u32x2*)&sh[r][cs*16 + q*4] = *(const u32x2*)o;
  }
  __syncthreads();
  int n = tid >> 2, ks = tid & 3;
  u16 tmp[16];
  #pragma unroll
  for (int j = 0; j < 16; ++j) tmp[j] = sh[ks*16 + j][n];
  u16* dp = dst + (size_t)(n0 + n)*dstK + k0 + ks*16;
  *(u32x4*)dp       = *(const u32x4*)tmp;
  *(u32x4*)(dp + 8) = *(const u32x4*)(tmp + 8);
}

__global__ __launch_bounds__(256) void prep_kernel(
    const float* __restrict__ x, const float* __restrict__ w_attn,
    const float* __restrict__ w_proj,
    u16* __restrict__ xb, u16* __restrict__ wta, u16* __restrict__ wtp)
{
  __shared__ u16 sh[64][68];
  const int bid = blockIdx.x, tid = threadIdx.x;
  if (bid < 1536) {                                  // x -> bf16
    int i = bid*256 + tid;
    float4 v = reinterpret_cast<const float4*>(x)[i];
    u16 o[4] = { f2bf(v.x), f2bf(v.y), f2bf(v.z), f2bf(v.w) };
    *reinterpret_cast<u32x2*>(xb + (size_t)i*4) = *(const u32x2*)o;
  } else if (bid < 1536 + 27) {                      // w_attn transpose
    int t = bid - 1536; int kt = t/9, nt = t%9;
    transpose64(w_attn, N3, wta, ND, kt*64, nt*64, sh, tid);
  } else {                                           // w_proj transpose
    int t = bid - 1563; int kt = t/3, nt = t%3;
    transpose64(w_proj, ND, wtp, ND, kt*64, nt*64, sh, tid);
  }
}

// ----------------------------------------------------------------- qkv ----
// [8192,192] @ [192,576] + b.  96-wide n-tiles (4 heads exactly).
// Q/K -> qp/kp [b][s][h][32] as FULL 64B rows (d24 = mask/1.0 fold, pad=0)
// V   -> vtp [b][h][32][s]; row d=24 = 1.0 (denominator ones-row)
__global__ __launch_bounds__(256) void qkv_kernel(
    const u16* __restrict__ xb, const u16* __restrict__ wta,
    const float* __restrict__ b_attn, const float* __restrict__ mask0,
    u16* __restrict__ qp, u16* __restrict__ kp, u16* __restrict__ vtp)
{
  __shared__ u16 tile[96*72];    // V path: [96][72]; Q/K path: [64][104]
  const int m0 = blockIdx.x*64, n0 = blockIdx.y*96;
  const int tid = threadIdx.x;
  const int w = tid >> 6, lane = tid & 63, c = lane & 15, g = lane >> 4;
  f32x4 acc[6] = {};
  const int ar = m0 + w*16 + c;
  #pragma unroll
  for (int ks = 0; ks < 6; ++ks) {
    bf16x8 af = *(const bf16x8*)(xb + (size_t)ar*ND + ks*32 + g*8);
    #pragma unroll
    for (int t = 0; t < 6; ++t) {
      bf16x8 bfr = *(const bf16x8*)(wta + (size_t)(n0 + t*16 + c)*ND + ks*32 + g*8);
      acc[t] = __builtin_amdgcn_mfma_f32_16x16x32_bf16(af, bfr, acc[t], 0, 0, 0);
    }
  }
  const int b = m0 >> 11, sb = m0 & (NS-1);
  if (n0 >= 384) {                                   // ---- V tiles ----
    const int h0 = (n0 - 384)/HD;                    // 0 or 4
    #pragma unroll
    for (int t = 0; t < 6; ++t) {
      float bias = b_attn[n0 + t*16 + c];
      #pragma unroll
      for (int r = 0; r < 4; ++r)
        tile[(t*16 + c)*72 + w*16 + g*4 + r] = f2bf(acc[t][r] + bias);
    }
    __syncthreads();
    if (tid < 200) {                                 // 96 data rows + 4 ones rows
      int row = tid >> 1, seg = tid & 1;
      if (row < 96) {
        int hl = row / HD, dv = row % HD;
        u16* dst = vtp + ((size_t)((b*NH + h0 + hl)*32 + dv))*NS + sb + seg*32;
        const u16* src = &tile[row*72 + seg*32];
        #pragma unroll
        for (int q = 0; q < 4; ++q)
          *(u32x4*)(dst + q*8) = *(const u32x4*)(src + q*8);
      } else {
        int hl = row - 96;
        u16* dst = vtp + ((size_t)((b*NH + h0 + hl)*32 + 24))*NS + sb + seg*32;
        u16 ones[8] = {0x3F80,0x3F80,0x3F80,0x3F80,0x3F80,0x3F80,0x3F80,0x3F80};
        #pragma unroll
        for (int q = 0; q < 4; ++q)
          *(u32x4*)(dst + q*8) = *(const u32x4*)ones;
      }
    }
  } else {                                           // ---- Q/K tiles ----
    const bool isQ = (n0 < 192);
    const float scl = isQ ? QSCALE : 1.0f;
    #pragma unroll
    for (int t = 0; t < 6; ++t) {
      float bias = b_attn[n0 + t*16 + c];
      #pragma unroll
      for (int r = 0; r < 4; ++r)
        tile[(w*16 + g*4 + r)*104 + t*16 + c] = f2bf((acc[t][r] + bias)*scl);
    }
    __syncthreads();
    int row = tid >> 2, run = tid & 3;
    int h0 = (n0 % 192)/HD;                          // 0 or 4
    u16 d24 = isQ ? (u16)0x3F80
                  : f2bf(mask0[b*NS + sb + row] * LOG2E);
    const u16* src = &tile[row*104 + run*24];        // 48B, 16B-aligned
    union { u32x4 q[4]; u16 s[32]; } buf;
    buf.q[0] = *(const u32x4*)(src);
    buf.q[1] = *(const u32x4*)(src + 8);
    buf.q[2] = *(const u32x4*)(src + 16);
    buf.s[24] = d24;
    #pragma unroll
    for (int j = 25; j < 32; ++j) buf.s[j] = 0;
    u16* dst = (isQ ? qp : kp)
             + ((size_t)((b*NS + sb + row)*NH + h0 + run))*32;
    #pragma unroll
    for (int q = 0; q < 4; ++q)
      *(u32x4*)(dst + q*8) = buf.q[q];
  }
}

// ---------------------------------------------------------------- attn ----
// 4 waves/block; block = 128 q-rows (4 q-tiles of 32) of one (b,h).
// K/V staged in LDS (reg-staged, double-buffered, 1 barrier per kv-tile of 64).
// Per wave: S^T = mfma(K,Q); in-register softmax; denominator via V ones-row.
__global__ __launch_bounds__(256) void attn_kernel(
    const u16* __restrict__ qp, const u16* __restrict__ kp,
    const u16* __restrict__ vtp, u16* __restrict__ ao)
{
  __shared__ u16 klds[2][64][40];   // K tile: 64 rows, 80B stride (pad)
  __shared__ u16 vlds[2][32][72];   // V^T tile: 32 d-rows x 64 s, 144B stride
  u16 (*ot)[32][40] = (u16(*)[32][40])klds;   // epilogue alias (after loop)

  const int bh = blockIdx.x;
  const int g  = 15 - (int)blockIdx.y;               // heavy blocks first
  const int b = bh >> 3, h = bh & 7;
  const int tid = threadIdx.x;
  const int w = tid >> 6, lane = tid & 63, c = lane & 31, hi = lane >> 5;
  const int q0 = g*128 + w*32;
  const int nt = 2*g + 2;

  const size_t rowstride = NH*32;                    // 256 u16 per s-row
  const size_t qkbase = (size_t)b*NS*rowstride + h*32;

  const u16* qrow = qp + qkbase + (size_t)(q0 + c)*rowstride;
  bf16x8 qf0 = *(const bf16x8*)(qrow + hi*8);
  bf16x8 qf1 = *(const bf16x8*)(qrow + 16 + hi*8);

  // staging roles (block-wide, independent of wave's q-work)
  const int krow = tid >> 2, kch = tid & 3;          // K: 64 rows x 4x16B
  const int vrow = tid >> 3, vch = tid & 7;          // V: 32 rows x 8x16B
  const u16* kgsrc = kp + qkbase + (size_t)krow*rowstride + kch*8;
  const u16* vgsrc = vtp + ((size_t)(bh*32 + vrow))*NS + vch*8;

  // prologue: stage tile 0
  u32x4 kreg = *(const u32x4*)(kgsrc);
  u32x4 vreg = *(const u32x4*)(vgsrc);
  *(u32x4*)&klds[0][krow][kch*8] = kreg;
  *(u32x4*)&vlds[0][vrow][vch*8] = vreg;
  __syncthreads();

  f32x16 o = {0};
  const f32x16 z16 = {0};
  float m = 0.f;

  for (int t = 0; t < nt; ++t) {
    const int cur = t & 1;
    if (t + 1 < nt) {                                // issue-early (T14)
      kreg = *(const u32x4*)(kgsrc + (size_t)(t+1)*64*rowstride);
      vreg = *(const u32x4*)(vgsrc + (t+1)*64);
    }
    const int kb0 = t*64;
    if (kb0 <= q0) {                                 // wave active this tile
      const bool a1 = (kb0 + 32 <= q0);              // chunk1 active
      // ---- QK^T chunk0 ----
      bf16x8 ka0 = *(const bf16x8*)&klds[cur][c][hi*8];
      bf16x8 ka1 = *(const bf16x8*)&klds[cur][c][16 + hi*8];
      f32x16 st = __builtin_amdgcn_mfma_f32_32x32x16_bf16(ka0, qf0, z16, 0, 0, 0);
      st        = __builtin_amdgcn_mfma_f32_32x32x16_bf16(ka1, qf1, st,  0, 0, 0);
      f32x16 su;
      if (a1) {                                      // ---- QK^T chunk1 ----
        bf16x8 kb0f = *(const bf16x8*)&klds[cur][32 + c][hi*8];
        bf16x8 kb1f = *(const bf16x8*)&klds[cur][32 + c][16 + hi*8];
        su = __builtin_amdgcn_mfma_f32_32x32x16_bf16(kb0f, qf0, z16, 0, 0, 0);
        su = __builtin_amdgcn_mfma_f32_32x32x16_bf16(kb1f, qf1, su,  0, 0, 0);
      }
      // ---- causal mask + per-lane max ----
      float pm = -3.0e38f;
      if (kb0 == q0) {                               // chunk0 is diagonal
        #pragma unroll
        for (int r = 0; r < 16; ++r) {
          int krel = (r & 3) + 8*(r >> 2) + 4*hi;
          float s = (krel > c) ? -3.0e38f : st[r];
          st[r] = s; pm = fmaxf(pm, s);
        }
      } else {
        #pragma unroll
        for (int r = 0; r < 16; ++r) pm = fmaxf(pm, st[r]);
      }
      if (a1) {
        if (kb0 + 32 == q0) {                        // chunk1 is diagonal
          #pragma unroll
          for (int r = 0; r < 16; ++r) {
            int krel = (r & 3) + 8*(r >> 2) + 4*hi;
            float s = (krel > c) ? -3.0e38f : su[r];
            su[r] = s; pm = fmaxf(pm, s);
          }
        } else {
          #pragma unroll
          for (int r = 0; r < 16; ++r) pm = fmaxf(pm, su[r]);
        }
      }
      // ---- defer-max online softmax ----
      if (!__all(pm - m <= 8.f)) {
        float pm2 = fmaxf(pm, __shfl_xor(pm, 32));
        float mn = fmaxf(m, pm2);
        float al = __builtin_amdgcn_exp2f(m - mn);
        #pragma unroll
        for (int r = 0; r < 16; ++r) o[r] *= al;
        m = mn;
      }
      #pragma unroll
      for (int r = 0; r < 16; ++r) st[r] = __builtin_amdgcn_exp2f(st[r] - m);
      if (a1) {
        #pragma unroll
        for (int r = 0; r < 16; ++r) su[r] = __builtin_amdgcn_exp2f(su[r] - m);
      }
      // ---- P^T -> B-frags (cvt_pk + permlane32_swap), PV chunk0 ----
      {
        u32 a0 = cvtpk(st[0], st[1]),  b0 = cvtpk(st[4], st[5]);
        u32 a1w = cvtpk(st[2], st[3]), b1 = cvtpk(st[6], st[7]);
        pswap(a0, b0); pswap(a1w, b1);
        u32 a2 = cvtpk(st[8], st[9]),  b2 = cvtpk(st[12], st[13]);
        u32 a3 = cvtpk(st[10], st[11]), b3 = cvtpk(st[14], st[15]);
        pswap(a2, b2); pswap(a3, b3);
        union { u32 wrd[4]; bf16x8 v; } pf0, pf1;
        pf0.wrd[0] = a0; pf0.wrd[1] = a1w; pf0.wrd[2] = b0; pf0.wrd[3] = b1;
        pf1.wrd[0] = a2; pf1.wrd[1] = a3;  pf1.wrd[2] = b2; pf1.wrd[3] = b3;
        bf16x8 va0 = *(const bf16x8*)&vlds[cur][c][hi*8];
        bf16x8 va1 = *(const bf16x8*)&vlds[cur][c][16 + hi*8];
        o = __builtin_amdgcn_mfma_f32_32x32x16_bf16(va0, pf0.v, o, 0, 0, 0);
        o = __builtin_amdgcn_mfma_f32_32x32x16_bf16(va1, pf1.v, o, 0, 0, 0);
      }
      if (a1) {                                      // ---- PV chunk1 ----
        u32 a0 = cvtpk(su[0], su[1]),  b0 = cvtpk(su[4], su[5]);
        u32 a1w = cvtpk(su[2], su[3]), b1 = cvtpk(su[6], su[7]);
        pswap(a0, b0); pswap(a1w, b1);
        u32 a2 = cvtpk(su[8], su[9]),  b2 = cvtpk(su[12], su[13]);
        u32 a3 = cvtpk(su[10], su[11]), b3 = cvtpk(su[14], su[15]);
        pswap(a2, b2); pswap(a3, b3);
        union { u32 wrd[4]; bf16x8 v; } pf0, pf1;
        pf0.wrd[0] = a0; pf0.wrd[1] = a1w; pf0.wrd[2] = b0; pf0.wrd[3] = b1;
        pf1.wrd[0] = a2; pf1.wrd[1] = a3;  pf1.wrd[2] = b2; pf1.wrd[3] = b3;
        bf16x8 va0 = *(const bf16x8*)&vlds[cur][c][32 + hi*8];
        bf16x8 va1 = *(const bf16x8*)&vlds[cur][c][48 + hi*8];
        o = __builtin_amdgcn_mfma_f32_32x32x16_bf16(va0, pf0.v, o, 0, 0, 0);
        o = __builtin_amdgcn_mfma_f32_32x32x16_bf16(va1, pf1.v, o, 0, 0, 0);
      }
    }
    // ---- write-late staging into the other buffer, then the tile barrier ----
    if (t + 1 < nt) {
      *(u32x4*)&klds[cur^1][krow][kch*8] = kreg;
      *(u32x4*)&vlds[cur^1][vrow][vch*8] = vreg;
    }
    __syncthreads();
  }

  // ---- epilogue: normalize (l rides in o row d=24), per-wave LDS transpose ----
  float lv = o[12];                                  // d==24 lives at r=12, hi=0
  float lo_ = __shfl_xor(lv, 32);
  float l = hi ? lo_ : lv;
  float inv = 1.0f / l;
  #pragma unroll
  for (int r = 0; r < 12; ++r) {
    int d = (r & 3) + 8*(r >> 2) + 4*hi;             // 0..23 across hi
    ot[w][c][d] = f2bf(o[r]*inv);
  }
  int q = lane >> 1, half = lane & 1;
  const u16* src = &ot[w][q][half*12];
  u32x2 w0 = *(const u32x2*)src;
  u32x2 w1 = *(const u32x2*)(src + 4);
  u32x2 w2 = *(const u32x2*)(src + 8);
  u16* dst = ao + ((size_t)(b*NS + q0 + q))*ND + h*HD + half*12;
  *(u32x2*)dst       = w0;
  *(u32x2*)(dst + 4) = w1;
  *(u32x2*)(dst + 8) = w2;
}

// ---------------------------------------------------------------- proj ----
__global__ __launch_bounds__(256) void proj_kernel(
    const u16* __restrict__ ao, const u16* __restrict__ wtp,
    const float* __restrict__ bp, float* __restrict__ out)
{
  const int m0 = blockIdx.x*64, n0 = blockIdx.y*64;
  const int tid = threadIdx.x;
  const int w = tid >> 6, lane = tid & 63, c = lane & 15, g = lane >> 4;
  f32x4 acc[4] = {};
  const int ar = m0 + w*16 + c;
  #pragma unroll
  for (int ks = 0; ks < 6; ++ks) {
    bf16x8 af = *(const bf16x8*)(ao + (size_t)ar*ND + ks*32 + g*8);
    #pragma unroll
    for (int t = 0; t < 4; ++t) {
      bf16x8 bfr = *(const bf16x8*)(wtp + (size_t)(n0 + t*16 + c)*ND + ks*32 + g*8);
      acc[t] = __builtin_amdgcn_mfma_f32_16x16x32_bf16(af, bfr, acc[t], 0, 0, 0);
    }
  }
  #pragma unroll
  for (int t = 0; t < 4; ++t) {
    int n = n0 + t*16 + c;
    float bias = bp[n];
    #pragma unroll
    for (int r = 0; r < 4; ++r) {
      int mm = m0 + w*16 + g*4 + r;
      out[(size_t)mm*ND + n] = acc[t][r] + bias;
    }
  }
}

// -------------------------------------------------------------- launch ----
extern "C" void kernel_launch(void* const* d_in, const int* in_sizes, int n_in,
                              void* d_out, int out_size, void* d_ws, size_t ws_size,
                              hipStream_t stream)
{
  const float* x      = (const float*)d_in[0];
  const float* mask0  = (const float*)d_in[1];
  const float* w_attn = (const float*)d_in[2];
  const float* b_attn = (const float*)d_in[3];
  const float* w_proj = (const float*)d_in[4];
  const float* b_proj = (const float*)d_in[5];
  float* out = (float*)d_out;

  char* ws = (char*)d_ws;
  u16* qp  = (u16*)(ws);                                  // 4 MB [b][s][h][32]
  u16* kp  = (u16*)(ws + ((size_t)4  << 20));             // 4 MB [b][s][h][32]
  u16* vtp = (u16*)(ws + ((size_t)8  << 20));             // 4 MB [b][h][32][s]
  u16* xb  = (u16*)(ws + ((size_t)12 << 20));             // 3 MB x bf16
  u16* wta = (u16*)(ws + ((size_t)15 << 20));             // 216 KB
  u16* wtp = (u16*)(ws + ((size_t)15 << 20) + 256*1024);  // 72 KB
  u16* ao  = (u16*)(ws + ((size_t)15 << 20) + 512*1024);  // 3 MB attn out bf16

  prep_kernel<<<1572, 256, 0, stream>>>(x, w_attn, w_proj, xb, wta, wtp);
  qkv_kernel<<<dim3(NM/64, 6), 256, 0, stream>>>(xb, wta, b_attn, mask0,
                                                 qp, kp, vtp);
  attn_kernel<<<dim3(NBH, 16), 256, 0, stream>>>(qp, kp, vtp, ao);
  proj_kernel<<<dim3(NM/64, ND/64), 256, 0, stream>>>(ao, wtp, b_proj, out);
}

// Round 5
// 133.889 us; speedup vs baseline: 1.2278x; 1.0405x over previous
//
#include <hip/hip_runtime.h>

typedef unsigned short u16;
typedef unsigned int u32;
typedef __bf16 bf16x8 __attribute__((ext_vector_type(8)));
typedef float f32x4 __attribute__((ext_vector_type(4)));
typedef float f32x16 __attribute__((ext_vector_type(16)));
typedef u32 u32x2 __attribute__((ext_vector_type(2)));
typedef u32 u32x4 __attribute__((ext_vector_type(4)));

#define NB 4
#define NS 2048
#define ND 192
#define NH 8
#define HD 24
#define NM (NB*NS)          // 8192 rows
#define N3 (3*ND)           // 576
#define NBH (NB*NH)         // 32
#define NROWS (NBH*NS)      // 65536 partial rows per part

#define LOG2E 1.4426950408889634f
// 1/sqrt(24) * log2(e): fold softmax scale and exp->exp2 conversion into Q
#define QSCALE (0.20412414523193152f * 1.4426950408889634f)

__device__ __forceinline__ u16 f2bf(float f){
  union { float f; unsigned u; } a; a.f = f;
  unsigned r = a.u + 0x7fffu + ((a.u >> 16) & 1u);   // round-to-nearest-even
  return (u16)(r >> 16);
}
__device__ __forceinline__ float b2f(u16 h){
  union { u32 u; float f; } a; a.u = ((u32)h) << 16; return a.f;
}
__device__ __forceinline__ u32 cvtpk(float lo, float hi){
  u32 r; asm("v_cvt_pk_bf16_f32 %0, %1, %2" : "=v"(r) : "v"(lo), "v"(hi)); return r;
}
// swaps high 32 lanes of a with low 32 lanes of b
__device__ __forceinline__ void pswap(u32 &a, u32 &b){
  asm("v_permlane32_swap_b32 %0, %1" : "+v"(a), "+v"(b));
}

// ---------------------------------------------------------------- prep ----
// weight transposes only (x conversion folded into qkv): 36 blocks
__device__ __forceinline__ void transpose64(
    const float* __restrict__ src, int srcN, u16* __restrict__ dst, int dstK,
    int k0, int n0, u16 (*sh)[68], int tid)
{
  int r = tid >> 2, cs = tid & 3;
  const float* sp = src + (size_t)(k0 + r)*srcN + n0 + cs*16;
  #pragma unroll
  for (int q = 0; q < 4; ++q) {
    float4 v = *(const float4*)(sp + q*4);
    u16 o[4] = { f2bf(v.x), f2bf(v.y), f2bf(v.z), f2bf(v.w) };
    *(u32x2*)&sh[r][cs*16 + q*4] = *(const u32x2*)o;
  }
  __syncthreads();
  int n = tid >> 2, ks = tid & 3;
  u16 tmp[16];
  #pragma unroll
  for (int j = 0; j < 16; ++j) tmp[j] = sh[ks*16 + j][n];
  u16* dp = dst + (size_t)(n0 + n)*dstK + k0 + ks*16;
  *(u32x4*)dp       = *(const u32x4*)tmp;
  *(u32x4*)(dp + 8) = *(const u32x4*)(tmp + 8);
}

__global__ __launch_bounds__(256) void prep_kernel(
    const float* __restrict__ w_attn, const float* __restrict__ w_proj,
    u16* __restrict__ wta, u16* __restrict__ wtp)
{
  __shared__ u16 sh[64][68];
  const int bid = blockIdx.x, tid = threadIdx.x;
  if (bid < 27) {                                    // w_attn transpose
    int kt = bid/9, nt = bid%9;
    transpose64(w_attn, N3, wta, ND, kt*64, nt*64, sh, tid);
  } else {                                           // w_proj transpose
    int t = bid - 27; int kt = t/3, nt = t%3;
    transpose64(w_proj, ND, wtp, ND, kt*64, nt*64, sh, tid);
  }
}

// ----------------------------------------------------------------- qkv ----
// [8192,192] @ [192,576] + b.  96-wide n-tiles (4 heads exactly).
// x read as fp32, converted to bf16 A-frags inline (cvt_pk).
// Q/K -> qp/kp [b][s][h][32] as FULL 64B rows (d24 = mask/1.0 fold, pad=0)
// V   -> vtp [b][h][32][s]; row d=24 = 1.0 (denominator ones-row)
__global__ __launch_bounds__(256) void qkv_kernel(
    const float* __restrict__ x, const u16* __restrict__ wta,
    const float* __restrict__ b_attn, const float* __restrict__ mask0,
    u16* __restrict__ qp, u16* __restrict__ kp, u16* __restrict__ vtp)
{
  __shared__ u16 tile[96*72];    // V path: [96][72]; Q/K path: [64][104]
  const int m0 = blockIdx.x*64, n0 = blockIdx.y*96;
  const int tid = threadIdx.x;
  const int w = tid >> 6, lane = tid & 63, c = lane & 15, g = lane >> 4;
  f32x4 acc[6] = {};
  const int ar = m0 + w*16 + c;
  const float* xrow = x + (size_t)ar*ND;
  #pragma unroll
  for (int ks = 0; ks < 6; ++ks) {
    float4 xa = *(const float4*)(xrow + ks*32 + g*8);
    float4 xc = *(const float4*)(xrow + ks*32 + g*8 + 4);
    union { u32 wrd[4]; bf16x8 v; } afu;
    afu.wrd[0] = cvtpk(xa.x, xa.y); afu.wrd[1] = cvtpk(xa.z, xa.w);
    afu.wrd[2] = cvtpk(xc.x, xc.y); afu.wrd[3] = cvtpk(xc.z, xc.w);
    bf16x8 af = afu.v;
    #pragma unroll
    for (int t = 0; t < 6; ++t) {
      bf16x8 bfr = *(const bf16x8*)(wta + (size_t)(n0 + t*16 + c)*ND + ks*32 + g*8);
      acc[t] = __builtin_amdgcn_mfma_f32_16x16x32_bf16(af, bfr, acc[t], 0, 0, 0);
    }
  }
  const int b = m0 >> 11, sb = m0 & (NS-1);
  if (n0 >= 384) {                                   // ---- V tiles ----
    const int h0 = (n0 - 384)/HD;                    // 0 or 4
    #pragma unroll
    for (int t = 0; t < 6; ++t) {
      float bias = b_attn[n0 + t*16 + c];
      #pragma unroll
      for (int r = 0; r < 4; ++r)
        tile[(t*16 + c)*72 + w*16 + g*4 + r] = f2bf(acc[t][r] + bias);
    }
    __syncthreads();
    if (tid < 200) {                                 // 96 data rows + 4 ones rows
      int row = tid >> 1, seg = tid & 1;
      if (row < 96) {
        int hl = row / HD, dv = row % HD;
        u16* dst = vtp + ((size_t)((b*NH + h0 + hl)*32 + dv))*NS + sb + seg*32;
        const u16* src = &tile[row*72 + seg*32];
        #pragma unroll
        for (int q = 0; q < 4; ++q)
          *(u32x4*)(dst + q*8) = *(const u32x4*)(src + q*8);
      } else {
        int hl = row - 96;
        u16* dst = vtp + ((size_t)((b*NH + h0 + hl)*32 + 24))*NS + sb + seg*32;
        u16 ones[8] = {0x3F80,0x3F80,0x3F80,0x3F80,0x3F80,0x3F80,0x3F80,0x3F80};
        #pragma unroll
        for (int q = 0; q < 4; ++q)
          *(u32x4*)(dst + q*8) = *(const u32x4*)ones;
      }
    }
  } else {                                           // ---- Q/K tiles ----
    const bool isQ = (n0 < 192);
    const float scl = isQ ? QSCALE : 1.0f;
    #pragma unroll
    for (int t = 0; t < 6; ++t) {
      float bias = b_attn[n0 + t*16 + c];
      #pragma unroll
      for (int r = 0; r < 4; ++r)
        tile[(w*16 + g*4 + r)*104 + t*16 + c] = f2bf((acc[t][r] + bias)*scl);
    }
    __syncthreads();
    int row = tid >> 2, run = tid & 3;
    int h0 = (n0 % 192)/HD;                          // 0 or 4
    u16 d24 = isQ ? (u16)0x3F80
                  : f2bf(mask0[b*NS + sb + row] * LOG2E);
    const u16* src = &tile[row*104 + run*24];        // 48B, 16B-aligned
    union { u32x4 q[4]; u16 s[32]; } buf;
    buf.q[0] = *(const u32x4*)(src);
    buf.q[1] = *(const u32x4*)(src + 8);
    buf.q[2] = *(const u32x4*)(src + 16);
    buf.s[24] = d24;
    #pragma unroll
    for (int j = 25; j < 32; ++j) buf.s[j] = 0;
    u16* dst = (isQ ? qp : kp)
             + ((size_t)((b*NS + sb + row)*NH + h0 + run))*32;
    #pragma unroll
    for (int q = 0; q < 4; ++q)
      *(u32x4*)(dst + q*8) = buf.q[q];
  }
}

// ---------------------------------------------------------------- attn ----
// 4 waves/block, 128 q-rows/block, kv-range split in 2 equal parts
// (part0 = tiles [0,g+1), part1 = [g+1,2g+2)). K/V staged in LDS,
// double-buffered, 1 barrier/tile. Partials (unnorm O + l@d24, m) -> po/pmf.
__global__ __launch_bounds__(256) void attn_kernel(
    const u16* __restrict__ qp, const u16* __restrict__ kp,
    const u16* __restrict__ vtp, u16* __restrict__ po, float* __restrict__ pmf)
{
  __shared__ u16 klds[2][64][40];   // K tile: 64 rows, 80B stride (pad)
  __shared__ u16 vlds[2][32][72];   // V^T tile: 32 d-rows x 64 s, 144B stride

  const int bh = blockIdx.x;
  const int g  = 15 - (int)blockIdx.y;               // heavy blocks first
  const int part = blockIdx.z;
  const int b = bh >> 3, h = bh & 7;
  const int tid = threadIdx.x;
  const int w = tid >> 6, lane = tid & 63, c = lane & 31, hi = lane >> 5;
  const int q0 = g*128 + w*32;
  const int t0 = part ? g + 1 : 0;
  const int ntp = g + 1;                             // tiles in this part

  const size_t rowstride = NH*32;                    // 256 u16 per s-row
  const size_t qkbase = (size_t)b*NS*rowstride + h*32;

  const u16* qrow = qp + qkbase + (size_t)(q0 + c)*rowstride;
  bf16x8 qf0 = *(const bf16x8*)(qrow + hi*8);
  bf16x8 qf1 = *(const bf16x8*)(qrow + 16 + hi*8);

  // staging roles (block-wide)
  const int krow = tid >> 2, kch = tid & 3;          // K: 64 rows x 4x16B
  const int vrow = tid >> 3, vch = tid & 7;          // V: 32 rows x 8x16B
  const u16* kgsrc = kp + qkbase + (size_t)(t0*64 + krow)*rowstride + kch*8;
  const u16* vgsrc = vtp + ((size_t)(bh*32 + vrow))*NS + t0*64 + vch*8;

  // prologue: stage first tile of this part
  u32x4 kreg = *(const u32x4*)(kgsrc);
  u32x4 vreg = *(const u32x4*)(vgsrc);
  *(u32x4*)&klds[0][krow][kch*8] = kreg;
  *(u32x4*)&vlds[0][vrow][vch*8] = vreg;
  __syncthreads();

  f32x16 o = {0};
  const f32x16 z16 = {0};
  float m = 0.f;

  for (int dt = 0; dt < ntp; ++dt) {
    const int cur = dt & 1;
    if (dt + 1 < ntp) {                              // issue-early (T14)
      kreg = *(const u32x4*)(kgsrc + (size_t)(dt+1)*64*rowstride);
      vreg = *(const u32x4*)(vgsrc + (dt+1)*64);
    }
    const int kb0 = (t0 + dt)*64;
    if (kb0 <= q0) {                                 // wave active this tile
      const bool a1 = (kb0 + 32 <= q0);              // chunk1 active
      // ---- QK^T chunk0 ----
      bf16x8 ka0 = *(const bf16x8*)&klds[cur][c][hi*8];
      bf16x8 ka1 = *(const bf16x8*)&klds[cur][c][16 + hi*8];
      __builtin_amdgcn_s_setprio(1);
      f32x16 st = __builtin_amdgcn_mfma_f32_32x32x16_bf16(ka0, qf0, z16, 0, 0, 0);
      st        = __builtin_amdgcn_mfma_f32_32x32x16_bf16(ka1, qf1, st,  0, 0, 0);
      __builtin_amdgcn_s_setprio(0);
      f32x16 su;
      if (a1) {                                      // ---- QK^T chunk1 ----
        bf16x8 kb0f = *(const bf16x8*)&klds[cur][32 + c][hi*8];
        bf16x8 kb1f = *(const bf16x8*)&klds[cur][32 + c][16 + hi*8];
        __builtin_amdgcn_s_setprio(1);
        su = __builtin_amdgcn_mfma_f32_32x32x16_bf16(kb0f, qf0, z16, 0, 0, 0);
        su = __builtin_amdgcn_mfma_f32_32x32x16_bf16(kb1f, qf1, su,  0, 0, 0);
        __builtin_amdgcn_s_setprio(0);
      }
      // ---- causal mask + per-lane max ----
      float pm = -3.0e38f;
      if (kb0 == q0) {                               // chunk0 is diagonal
        #pragma unroll
        for (int r = 0; r < 16; ++r) {
          int krel = (r & 3) + 8*(r >> 2) + 4*hi;
          float s = (krel > c) ? -3.0e38f : st[r];
          st[r] = s; pm = fmaxf(pm, s);
        }
      } else {
        #pragma unroll
        for (int r = 0; r < 16; ++r) pm = fmaxf(pm, st[r]);
      }
      if (a1) {
        if (kb0 + 32 == q0) {                        // chunk1 is diagonal
          #pragma unroll
          for (int r = 0; r < 16; ++r) {
            int krel = (r & 3) + 8*(r >> 2) + 4*hi;
            float s = (krel > c) ? -3.0e38f : su[r];
            su[r] = s; pm = fmaxf(pm, s);
          }
        } else {
          #pragma unroll
          for (int r = 0; r < 16; ++r) pm = fmaxf(pm, su[r]);
        }
      }
      // ---- defer-max online softmax ----
      if (!__all(pm - m <= 8.f)) {
        float pm2 = fmaxf(pm, __shfl_xor(pm, 32));
        float mn = fmaxf(m, pm2);
        float al = __builtin_amdgcn_exp2f(m - mn);
        #pragma unroll
        for (int r = 0; r < 16; ++r) o[r] *= al;
        m = mn;
      }
      #pragma unroll
      for (int r = 0; r < 16; ++r) st[r] = __builtin_amdgcn_exp2f(st[r] - m);
      if (a1) {
        #pragma unroll
        for (int r = 0; r < 16; ++r) su[r] = __builtin_amdgcn_exp2f(su[r] - m);
      }
      // ---- P^T -> B-frags (cvt_pk + permlane32_swap), PV chunk0 ----
      {
        u32 a0 = cvtpk(st[0], st[1]),  b0 = cvtpk(st[4], st[5]);
        u32 a1w = cvtpk(st[2], st[3]), b1 = cvtpk(st[6], st[7]);
        pswap(a0, b0); pswap(a1w, b1);
        u32 a2 = cvtpk(st[8], st[9]),  b2 = cvtpk(st[12], st[13]);
        u32 a3 = cvtpk(st[10], st[11]), b3 = cvtpk(st[14], st[15]);
        pswap(a2, b2); pswap(a3, b3);
        union { u32 wrd[4]; bf16x8 v; } pf0, pf1;
        pf0.wrd[0] = a0; pf0.wrd[1] = a1w; pf0.wrd[2] = b0; pf0.wrd[3] = b1;
        pf1.wrd[0] = a2; pf1.wrd[1] = a3;  pf1.wrd[2] = b2; pf1.wrd[3] = b3;
        bf16x8 va0 = *(const bf16x8*)&vlds[cur][c][hi*8];
        bf16x8 va1 = *(const bf16x8*)&vlds[cur][c][16 + hi*8];
        __builtin_amdgcn_s_setprio(1);
        o = __builtin_amdgcn_mfma_f32_32x32x16_bf16(va0, pf0.v, o, 0, 0, 0);
        o = __builtin_amdgcn_mfma_f32_32x32x16_bf16(va1, pf1.v, o, 0, 0, 0);
        __builtin_amdgcn_s_setprio(0);
      }
      if (a1) {                                      // ---- PV chunk1 ----
        u32 a0 = cvtpk(su[0], su[1]),  b0 = cvtpk(su[4], su[5]);
        u32 a1w = cvtpk(su[2], su[3]), b1 = cvtpk(su[6], su[7]);
        pswap(a0, b0); pswap(a1w, b1);
        u32 a2 = cvtpk(su[8], su[9]),  b2 = cvtpk(su[12], su[13]);
        u32 a3 = cvtpk(su[10], su[11]), b3 = cvtpk(su[14], su[15]);
        pswap(a2, b2); pswap(a3, b3);
        union { u32 wrd[4]; bf16x8 v; } pf0, pf1;
        pf0.wrd[0] = a0; pf0.wrd[1] = a1w; pf0.wrd[2] = b0; pf0.wrd[3] = b1;
        pf1.wrd[0] = a2; pf1.wrd[1] = a3;  pf1.wrd[2] = b2; pf1.wrd[3] = b3;
        bf16x8 va0 = *(const bf16x8*)&vlds[cur][c][32 + hi*8];
        bf16x8 va1 = *(const bf16x8*)&vlds[cur][c][48 + hi*8];
        __builtin_amdgcn_s_setprio(1);
        o = __builtin_amdgcn_mfma_f32_32x32x16_bf16(va0, pf0.v, o, 0, 0, 0);
        o = __builtin_amdgcn_mfma_f32_32x32x16_bf16(va1, pf1.v, o, 0, 0, 0);
        __builtin_amdgcn_s_setprio(0);
      }
    }
    // ---- write-late staging into the other buffer, then the tile barrier ----
    if (dt + 1 < ntp) {
      *(u32x4*)&klds[cur^1][krow][kch*8] = kreg;
      *(u32x4*)&vlds[cur^1][vrow][vch*8] = vreg;
    }
    __syncthreads();
  }

  // ---- epilogue: write unnormalized partial (l rides channel d=24) ----
  const int pidx = part*NROWS + bh*NS + q0 + c;
  u16* porow = po + (size_t)pidx*32;
  #pragma unroll
  for (int rr = 0; rr < 4; ++rr) {
    u32 lo = cvtpk(o[rr*4 + 0], o[rr*4 + 1]);
    u32 h2 = cvtpk(o[rr*4 + 2], o[rr*4 + 3]);
    u32x2 wv = {lo, h2};
    *(u32x2*)(porow + rr*8 + hi*4) = wv;
  }
  if (hi == 0) pmf[pidx] = (t0*64 <= q0) ? m : -3.0e38f;
}

// --------------------------------------------------------------- merge ----
// combine the two kv-partials, normalize, emit ao [B,S,D] bf16
__global__ __launch_bounds__(256) void merge_kernel(
    const u16* __restrict__ po, const float* __restrict__ pmf,
    u16* __restrict__ ao)
{
  int i = blockIdx.x*256 + threadIdx.x;              // 65536 = (bh, q)
  int bh = i >> 11, q = i & (NS-1);
  int b = bh >> 3, h = bh & 7;
  float m1 = pmf[i], m2 = pmf[NROWS + i];
  float M = fmaxf(m1, m2);
  float w1 = __builtin_amdgcn_exp2f(m1 - M);
  float w2 = __builtin_amdgcn_exp2f(m2 - M);
  const u16* r1 = po + (size_t)i*32;
  const u16* r2 = r1 + (size_t)NROWS*32;
  u16 a1[32], a2[32];
  #pragma unroll
  for (int q4 = 0; q4 < 4; ++q4) {
    *(u32x4*)(a1 + q4*8) = *(const u32x4*)(r1 + q4*8);
    *(u32x4*)(a2 + q4*8) = *(const u32x4*)(r2 + q4*8);
  }
  float l = b2f(a1[24])*w1 + b2f(a2[24])*w2;
  float inv = 1.0f / l;
  u16 ob[24];
  #pragma unroll
  for (int d = 0; d < 24; ++d)
    ob[d] = f2bf((b2f(a1[d])*w1 + b2f(a2[d])*w2)*inv);
  u16* dst = ao + ((size_t)(b*NS + q))*ND + h*HD;
  #pragma unroll
  for (int q4 = 0; q4 < 3; ++q4)
    *(u32x4*)(dst + q4*8) = *(const u32x4*)(ob + q4*8);
}

// ---------------------------------------------------------------- proj ----
__global__ __launch_bounds__(256) void proj_kernel(
    const u16* __restrict__ ao, const u16* __restrict__ wtp,
    const float* __restrict__ bp, float* __restrict__ out)
{
  const int m0 = blockIdx.x*64, n0 = blockIdx.y*64;
  const int tid = threadIdx.x;
  const int w = tid >> 6, lane = tid & 63, c = lane & 15, g = lane >> 4;
  f32x4 acc[4] = {};
  const int ar = m0 + w*16 + c;
  #pragma unroll
  for (int ks = 0; ks < 6; ++ks) {
    bf16x8 af = *(const bf16x8*)(ao + (size_t)ar*ND + ks*32 + g*8);
    #pragma unroll
    for (int t = 0; t < 4; ++t) {
      bf16x8 bfr = *(const bf16x8*)(wtp + (size_t)(n0 + t*16 + c)*ND + ks*32 + g*8);
      acc[t] = __builtin_amdgcn_mfma_f32_16x16x32_bf16(af, bfr, acc[t], 0, 0, 0);
    }
  }
  #pragma unroll
  for (int t = 0; t < 4; ++t) {
    int n = n0 + t*16 + c;
    float bias = bp[n];
    #pragma unroll
    for (int r = 0; r < 4; ++r) {
      int mm = m0 + w*16 + g*4 + r;
      out[(size_t)mm*ND + n] = acc[t][r] + bias;
    }
  }
}

// -------------------------------------------------------------- launch ----
extern "C" void kernel_launch(void* const* d_in, const int* in_sizes, int n_in,
                              void* d_out, int out_size, void* d_ws, size_t ws_size,
                              hipStream_t stream)
{
  const float* x      = (const float*)d_in[0];
  const float* mask0  = (const float*)d_in[1];
  const float* w_attn = (const float*)d_in[2];
  const float* b_attn = (const float*)d_in[3];
  const float* w_proj = (const float*)d_in[4];
  const float* b_proj = (const float*)d_in[5];
  float* out = (float*)d_out;

  char* ws = (char*)d_ws;
  u16*   qp  = (u16*)(ws);                                  // 4 MB [b][s][h][32]
  u16*   kp  = (u16*)(ws + ((size_t)4  << 20));             // 4 MB [b][s][h][32]
  u16*   vtp = (u16*)(ws + ((size_t)8  << 20));             // 4 MB [b][h][32][s]
  u16*   wta = (u16*)(ws + ((size_t)12 << 20));             // 216 KB
  u16*   wtp = (u16*)(ws + ((size_t)12 << 20) + 256*1024);  // 72 KB
  u16*   ao  = (u16*)(ws + ((size_t)12 << 20) + 512*1024);  // 3 MB attn out bf16
  u16*   po  = (u16*)(ws + ((size_t)16 << 20));             // 8 MB partials
  float* pmf = (float*)(ws + ((size_t)24 << 20));           // 512 KB running max
  // total ws use: 24.5 MB

  prep_kernel<<<36, 256, 0, stream>>>(w_attn, w_proj, wta, wtp);
  qkv_kernel<<<dim3(NM/64, 6), 256, 0, stream>>>(x, wta, b_attn, mask0,
                                                 qp, kp, vtp);
  attn_kernel<<<dim3(NBH, 16, 2), 256, 0, stream>>>(qp, kp, vtp, po, pmf);
  merge_kernel<<<256, 256, 0, stream>>>(po, pmf, ao);
  proj_kernel<<<dim3(NM/64, ND/64), 256, 0, stream>>>(ao, wtp, b_proj, out);
}